// Round 1
// baseline (4148.080 us; speedup 1.0000x reference)
//
#include <hip/hip_runtime.h>
#include <math.h>

#define TT   64    // T_in == T_out
#define BB   64    // batch
#define HH   256   // hidden
#define VV   32000 // vocab
#define NG   1024  // 4*H gate rows
#define KK   256   // GEMM K (always H)

typedef __bf16 bf16x8 __attribute__((ext_vector_type(8)));
typedef float  f32x4  __attribute__((ext_vector_type(4)));

// ---------------- embedding gather ----------------
__global__ void embed_kernel(const int* __restrict__ tok, const float* __restrict__ tab,
                             float* __restrict__ X, int shifted) {
  int blk = blockIdx.x;          // t*B + b
  int t = blk >> 6, b = blk & 63;
  int id;
  if (shifted) id = (t == 0) ? 0 : tok[(t - 1) * BB + b];
  else         id = tok[t * BB + b];
  const float4* src = (const float4*)(tab + (long)id * HH);
  float4* dst = (float4*)(X + (long)blk * HH);
  dst[threadIdx.x] = src[threadIdx.x];   // 64 threads * float4 = 256 floats
}

// ---------------- weight packing ----------------
// Row permutation r' = 4*j + g  <->  r = g*256 + j  (gate-interleave per hidden unit)
__global__ void pack_wih(const float* __restrict__ eW, const float* __restrict__ dW,
                         const float* __restrict__ ebi, const float* __restrict__ ebh,
                         const float* __restrict__ dbi, const float* __restrict__ dbh,
                         float* __restrict__ Wpk, float* __restrict__ bpk) {
  int L = blockIdx.y;            // 0..5
  int rp = blockIdx.x;           // 0..1023
  int j = rp >> 2, g = rp & 3;
  int r = g * HH + j;
  const float* src = (L < 3 ? eW + (long)L * NG * HH : dW + (long)(L - 3) * NG * HH) + (long)r * HH;
  float* dst = Wpk + ((long)L * NG + rp) * HH;
  ((float4*)dst)[threadIdx.x] = ((const float4*)src)[threadIdx.x];  // 64 thr * float4
  if (threadIdx.x == 0) {
    const float* bi = (L < 3 ? ebi + L * NG : dbi + (L - 3) * NG);
    const float* bh = (L < 3 ? ebh + L * NG : dbh + (L - 3) * NG);
    bpk[(long)L * NG + rp] = bi[r] + bh[r];
  }
}

// WT[L][k][r'] = Whh[L][g*256+j][k]  (transposed + gate-interleaved)
__global__ void pack_whhT(const float* __restrict__ eW, const float* __restrict__ dW,
                          float* __restrict__ WT) {
  int L = blockIdx.y;            // 0..5
  int k = blockIdx.x;            // 0..255
  const float* src = (L < 3 ? eW + (long)L * NG * HH : dW + (long)(L - 3) * NG * HH);
  float* dst = WT + ((long)L * HH + k) * NG;
  int t = threadIdx.x;           // 0..255 -> j = t, g = 0..3
  float4 v;
  v.x = src[((long)(0 * HH + t)) * HH + k];
  v.y = src[((long)(1 * HH + t)) * HH + k];
  v.z = src[((long)(2 * HH + t)) * HH + k];
  v.w = src[((long)(3 * HH + t)) * HH + k];
  ((float4*)dst)[t] = v;
}

// ---------------- helpers ----------------
__device__ __forceinline__ unsigned long long shfl_xor_u64(unsigned long long v, int m) {
  unsigned lo = (unsigned)v, hi = (unsigned)(v >> 32);
  lo = __shfl_xor(lo, m);
  hi = __shfl_xor(hi, m);
  return ((unsigned long long)hi << 32) | lo;
}

__device__ __forceinline__ unsigned bf_rne(float x) {  // fp32 -> bf16 bits (RNE)
  unsigned u = __float_as_uint(x);
  return (u + 0x7FFFu + ((u >> 16) & 1u)) >> 16;
}
// split x ~= hi + lo, both bf16 (residual ~2^-18 |x|)
__device__ __forceinline__ void bf_split4(float4 v, short4& hi, short4& lo) {
  unsigned h0 = bf_rne(v.x), h1 = bf_rne(v.y), h2 = bf_rne(v.z), h3 = bf_rne(v.w);
  hi = make_short4((short)h0, (short)h1, (short)h2, (short)h3);
  lo = make_short4((short)bf_rne(v.x - __uint_as_float(h0 << 16)),
                   (short)bf_rne(v.y - __uint_as_float(h1 << 16)),
                   (short)bf_rne(v.z - __uint_as_float(h2 << 16)),
                   (short)bf_rne(v.w - __uint_as_float(h3 << 16)));
}

// ---------------- split-bf16 MFMA GEMM: C[M,N] = A[M,256]*B[N,256]^T + bias ----------------
// 128x128 tile, 256 threads = 4 waves (2x2), each wave 64x64 via 4x4 frags of 16x16x32.
// fp32 accuracy via 3 passes: Ahi*Bhi + Alo*Bhi + Ahi*Blo (err ~3e-6, fp32-reorder class).
// LDS tiles XOR-swizzled (T2): row-major [128][64]bf16 is 16-way bank-conflicted otherwise.
// Optional fused per-(row, 64-col segment) argmax -> amax[m][tile*2+wn], 500 segments.
__global__ __launch_bounds__(256) void gemm_mfma(
    const float* __restrict__ A, const float* __restrict__ B,
    const float* __restrict__ bias, float* __restrict__ C,
    int N, unsigned long long* __restrict__ amax) {
  __shared__ short lds[4 * 128 * 64];       // Ah | Al | Bh | Bl = 64 KB
  short* Ah = lds;
  short* Al = Ah + 128 * 64;
  short* Bh = Al + 128 * 64;
  short* Bl = Bh + 128 * 64;
  const int t = threadIdx.x;
  const int lane = t & 63;
  const int wid = t >> 6;
  const int wm = wid >> 1, wn = wid & 1;    // 2x2 wave grid
  const int lx = lane & 15, lg = lane >> 4;
  const int m0 = blockIdx.y * 128, n0 = blockIdx.x * 128;
  f32x4 acc[4][4] = {};                     // [mf][nf], D frag: col=lane&15, row=lg*4+reg

  for (int kc = 0; kc < KK; kc += 64) {
    // ---- stage 128x64 fp32 chunk of A and B -> hi/lo bf16, swizzled ----
    #pragma unroll
    for (int p = 0; p < 8; p++) {
      int f   = t + 256 * p;        // float4 index in the 128x16 float4 tile
      int row = f >> 4;             // 0..127
      int c4  = f & 15;             // float4 within row (coalesced across lanes)
      float4 av = *(const float4*)(A + (long)(m0 + row) * KK + kc + c4 * 4);
      float4 bv = *(const float4*)(B + (long)(n0 + row) * KK + kc + c4 * 4);
      int boff = row * 128 + ((c4 * 8) ^ ((row & 7) << 4));  // byte offset, 8B piece
      short4 h4, l4;
      bf_split4(av, h4, l4);
      *(short4*)((char*)Ah + boff) = h4;
      *(short4*)((char*)Al + boff) = l4;
      bf_split4(bv, h4, l4);
      *(short4*)((char*)Bh + boff) = h4;
      *(short4*)((char*)Bl + boff) = l4;
    }
    __syncthreads();
    #pragma unroll
    for (int ks = 0; ks < 2; ks++) {        // two K=32 steps per chunk
      bf16x8 ah[4], al[4], bh[4], bl[4];
      #pragma unroll
      for (int q = 0; q < 4; q++) {
        int ra = wm * 64 + q * 16 + lx;
        int ca = (ks * 64 + lg * 16) ^ ((ra & 7) << 4);
        ah[q] = *(const bf16x8*)((const char*)Ah + ra * 128 + ca);
        al[q] = *(const bf16x8*)((const char*)Al + ra * 128 + ca);
        int rb = wn * 64 + q * 16 + lx;
        int cb = (ks * 64 + lg * 16) ^ ((rb & 7) << 4);
        bh[q] = *(const bf16x8*)((const char*)Bh + rb * 128 + cb);
        bl[q] = *(const bf16x8*)((const char*)Bl + rb * 128 + cb);
      }
      #pragma unroll
      for (int mf = 0; mf < 4; mf++)
        #pragma unroll
        for (int nf = 0; nf < 4; nf++) {
          acc[mf][nf] = __builtin_amdgcn_mfma_f32_16x16x32_bf16(ah[mf], bh[nf], acc[mf][nf], 0, 0, 0);
          acc[mf][nf] = __builtin_amdgcn_mfma_f32_16x16x32_bf16(al[mf], bh[nf], acc[mf][nf], 0, 0, 0);
          acc[mf][nf] = __builtin_amdgcn_mfma_f32_16x16x32_bf16(ah[mf], bl[nf], acc[mf][nf], 0, 0, 0);
        }
    }
    __syncthreads();
  }

  // ---- epilogue: bias, store, fused argmax ----
  float bv[4];
  #pragma unroll
  for (int nf = 0; nf < 4; nf++) bv[nf] = bias[n0 + wn * 64 + nf * 16 + lx];
  #pragma unroll
  for (int mf = 0; mf < 4; mf++) {
    #pragma unroll
    for (int r = 0; r < 4; r++) {
      int m = m0 + wm * 64 + mf * 16 + lg * 4 + r;
      float best = -3.0e38f; int bi = 0;
      #pragma unroll
      for (int nf = 0; nf < 4; nf++) {
        int col = n0 + wn * 64 + nf * 16 + lx;
        float o = acc[mf][nf][r] + bv[nf];
        C[(long)m * N + col] = o;
        if (o > best) { best = o; bi = col; }   // strict > keeps lowest col on tie
      }
      if (amax) {
        unsigned uo = __float_as_uint(best);
        uo = (uo >> 31) ? ~uo : (uo | 0x80000000u);   // orderable float bits
        unsigned long long key = ((unsigned long long)uo << 32) | (unsigned)(0xFFFFFFFFu - bi);
        #pragma unroll
        for (int s2 = 1; s2 < 16; s2 <<= 1) {   // reduce over the 16-lane col group
          unsigned long long o2 = shfl_xor_u64(key, s2);
          if (o2 > key) key = o2;
        }
        if (lx == 0) amax[(long)m * 500 + blockIdx.x * 2 + wn] = key;
      }
    }
  }
}

// reduce per-row segment keys -> float index
__global__ void argmax_fin(const unsigned long long* __restrict__ amax,
                           float* __restrict__ out1, int ntiles) {
  int row = blockIdx.x;
  int t = threadIdx.x;   // 64
  unsigned long long key = 0ull;
  for (int c = t; c < ntiles; c += 64) {
    unsigned long long k = amax[(long)row * ntiles + c];
    if (k > key) key = k;
  }
  #pragma unroll
  for (int s = 1; s < 64; s <<= 1) {
    unsigned long long o = shfl_xor_u64(key, s);
    if (o > key) key = o;
  }
  if (t == 0) out1[row] = (float)(0xFFFFFFFFu - (unsigned)(key & 0xFFFFFFFFu));
}

// ---------------- LSTM recurrence: 1 block per batch, 1024 thr = 4-way K-split ----------------
// Was 256 thr (1 wave/SIMD, latency-starved). Now thread (s,j): partial gates of unit j over
// k in [64s,64s+64); LDS reduce; s==0 does the pointwise update. 16 waves/CU = 4/SIMD.
__global__ __launch_bounds__(1024) void lstm_recur(
    const float* __restrict__ G, const float* __restrict__ WT,
    const float* __restrict__ h0, int h0s,
    const float* __restrict__ c0, int c0s,
    float* __restrict__ Hout, float* __restrict__ hfin, float* __restrict__ cfin) {
  __shared__ float h_lds[HH];
  __shared__ float4 part[3][HH];   // partials from s=1..3 (12 KB)
  int b = blockIdx.x;
  int j = threadIdx.x & 255;       // hidden unit
  int s = threadIdx.x >> 8;        // k-slice 0..3
  int k0 = s * 64;
  float c = 0.f;
  if (s == 0) {
    c = c0[b * c0s + j];
    h_lds[j] = h0[b * h0s + j];
  }
  __syncthreads();
  const float4* WT4 = (const float4*)WT;   // [256][256] float4 rows (gate-interleaved)
  for (int t = 0; t < TT; t++) {
    float4 acc;
    if (s == 0) acc = ((const float4*)(G + ((long)(t * BB + b)) * NG))[j];  // pre-gates
    else { acc.x = 0.f; acc.y = 0.f; acc.z = 0.f; acc.w = 0.f; }
    #pragma unroll 4
    for (int k = k0; k < k0 + 64; k += 4) {
      float4 h4 = *(const float4*)&h_lds[k];         // broadcast across the wave
      float4 w0 = WT4[(long)(k + 0) * HH + j];
      float4 w1 = WT4[(long)(k + 1) * HH + j];
      float4 w2 = WT4[(long)(k + 2) * HH + j];
      float4 w3 = WT4[(long)(k + 3) * HH + j];
      acc.x += h4.x * w0.x; acc.y += h4.x * w0.y; acc.z += h4.x * w0.z; acc.w += h4.x * w0.w;
      acc.x += h4.y * w1.x; acc.y += h4.y * w1.y; acc.z += h4.y * w1.z; acc.w += h4.y * w1.w;
      acc.x += h4.z * w2.x; acc.y += h4.z * w2.y; acc.z += h4.z * w2.z; acc.w += h4.z * w2.w;
      acc.x += h4.w * w3.x; acc.y += h4.w * w3.y; acc.z += h4.w * w3.z; acc.w += h4.w * w3.w;
    }
    if (s) part[s - 1][j] = acc;
    __syncthreads();                 // partials visible; also: all h_lds reads for step t done
    if (s == 0) {
      float4 p1 = part[0][j], p2 = part[1][j], p3 = part[2][j];
      float gi = acc.x + p1.x + p2.x + p3.x;
      float gf = acc.y + p1.y + p2.y + p3.y;
      float gg = acc.z + p1.z + p2.z + p3.z;
      float go = acc.w + p1.w + p2.w + p3.w;
      float i_ = 1.f / (1.f + expf(-gi));
      float f_ = 1.f / (1.f + expf(-gf));
      float g_ = tanhf(gg);
      float o_ = 1.f / (1.f + expf(-go));
      c = f_ * c + i_ * g_;
      float hn = o_ * tanhf(c);
      h_lds[j] = hn;
      Hout[((long)(t * BB + b)) * HH + j] = hn;
    }
    __syncthreads();                 // h_lds updated before next step's reads
  }
  if (s == 0) {
    hfin[b * HH + j] = h_lds[j];
    cfin[b * HH + j] = c;
  }
}

// ---------------- host orchestration ----------------
extern "C" void kernel_launch(void* const* d_in, const int* in_sizes, int n_in,
                              void* d_out, int out_size, void* d_ws, size_t ws_size,
                              hipStream_t stream) {
  const int*   inputs  = (const int*)d_in[0];
  const int*   targets = (const int*)d_in[1];
  const float* enc_emb = (const float*)d_in[2];
  const float* enc_Wih = (const float*)d_in[3];
  const float* enc_Whh = (const float*)d_in[4];
  const float* enc_bih = (const float*)d_in[5];
  const float* enc_bhh = (const float*)d_in[6];
  const float* hidden0 = (const float*)d_in[7];
  const float* cell0   = (const float*)d_in[8];
  const float* dec_emb = (const float*)d_in[9];
  const float* dec_Wih = (const float*)d_in[10];
  const float* dec_Whh = (const float*)d_in[11];
  const float* dec_bih = (const float*)d_in[12];
  const float* dec_bhh = (const float*)d_in[13];
  const float* fc_W    = (const float*)d_in[14];
  const float* fc_b    = (const float*)d_in[15];

  float* out0 = (float*)d_out;
  float* out1 = out0 + (long)TT * BB * VV;

  float* X   = (float*)d_ws;                 // [4096,256]   4 MB  (layer I/O sequence)
  float* G   = X   + (long)4096 * 256;       // [4096,1024] 16 MB  (pre-gates)
  float* Wpk = G   + (long)4096 * 1024;      // [6,1024,256] 6 MB
  float* WT  = Wpk + (long)6 * 1024 * 256;   // [6,256,1024] 6 MB
  float* bpk = WT  + (long)6 * 256 * 1024;   // [6,1024]
  float* hst = bpk + 6 * 1024;               // enc final h [3,64,256]
  float* cst = hst + 3 * 64 * 256;           // enc final c [3,64,256]
  float* hsc = cst + 3 * 64 * 256;           // dec scratch h
  float* csc = hsc + 64 * 256;               // dec scratch c
  unsigned long long* amax = (unsigned long long*)G;  // overlay: G dead before FC (16.38<=16.77MB)

  // weight packing (all 6 layers) + encoder embedding
  embed_kernel<<<4096, 64, 0, stream>>>(inputs, enc_emb, X, 0);
  pack_wih<<<dim3(1024, 6), 64, 0, stream>>>(enc_Wih, dec_Wih, enc_bih, enc_bhh,
                                             dec_bih, dec_bhh, Wpk, bpk);
  pack_whhT<<<dim3(256, 6), 256, 0, stream>>>(enc_Whh, dec_Whh, WT);

  // encoder: 3 layers
  for (int l = 0; l < 3; l++) {
    gemm_mfma<<<dim3(8, 32), 256, 0, stream>>>(X, Wpk + (long)l * NG * HH,
                                               bpk + l * NG, G, NG, nullptr);
    lstm_recur<<<64, 1024, 0, stream>>>(G, WT + (long)l * HH * NG,
                                        hidden0 + l * HH, 0, cell0 + l * HH, 0,
                                        X, hst + (long)l * BB * HH, cst + (long)l * BB * HH);
  }

  // decoder: teacher-forced input embedding, 3 layers seeded from encoder finals
  embed_kernel<<<4096, 64, 0, stream>>>(targets, dec_emb, X, 1);
  for (int l = 0; l < 3; l++) {
    gemm_mfma<<<dim3(8, 32), 256, 0, stream>>>(X, Wpk + (long)(3 + l) * NG * HH,
                                               bpk + (3 + l) * NG, G, NG, nullptr);
    lstm_recur<<<64, 1024, 0, stream>>>(G, WT + (long)(3 + l) * HH * NG,
                                        hst + (long)l * BB * HH, HH,
                                        cst + (long)l * BB * HH, HH,
                                        X, hsc, csc);
  }

  // FC head (split-bf16 MFMA) + fused per-64-col argmax, then finalize
  gemm_mfma<<<dim3(250, 32), 256, 0, stream>>>(X, fc_W, fc_b, out0, VV, amax);
  argmax_fin<<<4096, 64, 0, stream>>>(amax, out1, 500);
}